// Round 5
// baseline (578.319 us; speedup 1.0000x reference)
//
#include <hip/hip_runtime.h>
#include <hip/hip_bf16.h>

#define STEPS 100
#define DTC 0.001f

typedef __attribute__((ext_vector_type(8))) short bf16x8;
typedef __attribute__((ext_vector_type(4))) float f32x4;

__device__ __forceinline__ void gload16(const void* g, void* l) {
  __builtin_amdgcn_global_load_lds(
      (const __attribute__((address_space(1))) void*)g,
      (__attribute__((address_space(3))) void*)l,
      16, 0, 0);
}

__device__ __forceinline__ unsigned short f2bu(float f) {
  __hip_bfloat16 h = __float2bfloat16(f);
  return *reinterpret_cast<unsigned short*>(&h);
}
__device__ __forceinline__ float bu2f(unsigned short u) {
  return __uint_as_float(((unsigned)u) << 16);
}

// ---------------- fused front: enc1+enc2+enc3+hopf (all row-b-local, fp32) ----------

__global__ __launch_bounds__(512)
void front(const float* __restrict__ ms_in, const float* __restrict__ rs_in,
           const float* __restrict__ z,
           const float* __restrict__ Wms, const float* __restrict__ bms,
           const float* __restrict__ Wrs, const float* __restrict__ brs,
           const float* __restrict__ Wc, const float* __restrict__ bc,
           const float* __restrict__ Wmu, const float* __restrict__ bmu,
           const float* __restrict__ Wb, const float* __restrict__ bbias,
           const float* __restrict__ Wom, const float* __restrict__ bom,
           __hip_bfloat16* __restrict__ A0, float* __restrict__ z_out,
           float* __restrict__ om_out, float* __restrict__ mu_out,
           float* __restrict__ bb_out, int* __restrict__ flags) {
  const int b = blockIdx.x;
  const int n = threadIdx.x;  // 512
  if (b == 0) flags[n] = 0;   // zero stream-K flags (512 ints) before GEMMs
  __shared__ float sIn[192];
  __shared__ float stA[512];
  __shared__ float stB[512];
  if (n < 64) sIn[n] = ms_in[b * 64 + n];
  else if (n < 192) sIn[n] = rs_in[b * 128 + (n - 64)];
  __syncthreads();
  // enc1
  float a1;
  if (n < 256) {
    a1 = bms[n];
    for (int k = 0; k < 64; ++k) a1 += sIn[k] * Wms[k * 256 + n];
  } else {
    int nn = n - 256;
    a1 = brs[nn];
    for (int k = 0; k < 128; ++k) a1 += sIn[64 + k] * Wrs[k * 256 + nn];
  }
  stA[n] = fmaxf(a1, 0.f);
  __syncthreads();
  // enc2
  float a2 = bc[n];
  for (int k = 0; k < 512; ++k) a2 += stA[k] * Wc[k * 512 + n];
  stB[n] = fmaxf(a2, 0.f);
  __syncthreads();
  // enc3: mu, b, omega
  float am = bmu[n], ab = bbias[n];
  for (int k = 0; k < 512; ++k) {
    float sv = stB[k];
    am += sv * Wmu[k * 512 + n];
    ab += sv * Wb[k * 512 + n];
  }
  const float muv = fabsf(fmaxf(am, 0.f));
  const float bbv = fabsf(fmaxf(ab, 0.f));
  mu_out[b * 512 + n] = muv;
  bb_out[b * 512 + n] = bbv;
  stA[n] = stB[n] * Wom[n];  // W_om is [512,1]; reuse stA as reduction buffer
  __syncthreads();
  for (int off = 256; off > 0; off >>= 1) {
    if (n < off) stA[n] += stA[n + off];
    __syncthreads();
  }
  const float om = fabsf(fmaxf(stA[0] + bom[0], 0.f));
  if (n == 0) om_out[b] = om;
  // hopf trajectory (fp32 state; bf16 GEMM input, M-order m = b*100 + t)
  float x = z[b * 1024 + n];
  float y = z[b * 1024 + 512 + n];
  const float w = om * (float)(n + 1);
  for (int t = 0; t < STEPS; ++t) {
    float r2 = x * x + y * y;
    float g = muv - r2;
    float nx = x + DTC * (g * x - w * y + bbv);
    float ny = y + DTC * (g * y + w * x);
    x = nx; y = ny;
    if (t == 0) {
      z_out[b * 1024 + n] = x;
      z_out[b * 1024 + 512 + n] = y;
    }
    size_t row = (size_t)b * STEPS + t;
    A0[row * 1024 + n] = __float2bfloat16(x);
    A0[row * 1024 + 512 + n] = __float2bfloat16(y);
  }
}

// ---------------- all 10 weight transposes in one kernel ----------------
// job tables mirror round-4's 10 tpack launches exactly.
__constant__ int    jSrcC[10] = {0, 1, 1, 0, 2, 3, 3, 2, 4, 5};
__constant__ float  jSgnC[10] = {1.f, 1.f, -1.f, 1.f, 1.f, 1.f, -1.f, 1.f, 1.f, -1.f};
__constant__ int    jCC[10]   = {1024, 1024, 1024, 1024, 512, 512, 512, 512, 256, 256};
__constant__ int    jDstC[10] = {0, 0, 0, 0, 1, 1, 1, 1, 2, 2};
__constant__ int    jDsC[10]  = {1024, 1024, 1024, 1024, 2048, 2048, 2048, 2048, 1024, 1024};
__constant__ long   jOffC[10] = {0, 1048576, 512, 1049088, 0, 1048576, 1024, 1049600, 0, 512};

__global__ void tpack_all(const float* __restrict__ Wr0, const float* __restrict__ Wi0,
                          const float* __restrict__ Wr1, const float* __restrict__ Wi1,
                          const float* __restrict__ Wr2, const float* __restrict__ Wi2,
                          __hip_bfloat16* __restrict__ BT0, __hip_bfloat16* __restrict__ BT1,
                          __hip_bfloat16* __restrict__ BT2) {
  __shared__ float tile[32][33];
  const int bid = blockIdx.x;
  int j, w;
  if (bid < 4096) { j = bid >> 9; w = bid & 511; }
  else            { j = 8 + ((bid - 4096) >> 7); w = (bid - 4096) & 127; }
  const float* srcs[6] = {Wr0, Wi0, Wr1, Wi1, Wr2, Wi2};
  __hip_bfloat16* dsts[3] = {BT0, BT1, BT2};
  const float* src = srcs[jSrcC[j]];
  __hip_bfloat16* dst = dsts[jDstC[j]] + jOffC[j];
  const int C = jCC[j], ds = jDsC[j];
  const float sign = jSgnC[j];
  const int ncb = C >> 5;
  const int cb = (w % ncb) * 32, rb = (w / ncb) * 32;
  const int tx = threadIdx.x, ty = threadIdx.y;  // (32,8)
#pragma unroll
  for (int i = 0; i < 32; i += 8)
    tile[ty + i][tx] = src[(size_t)(rb + ty + i) * C + (cb + tx)];
  __syncthreads();
#pragma unroll
  for (int i = 0; i < 32; i += 8)
    dst[(size_t)(cb + ty + i) * ds + (rb + tx)] = __float2bfloat16(sign * tile[tx][ty + i]);
}

// ---------------- 128^2 bf16 MFMA GEMM (kept for GEMM3) ----------------

template <int OUT_BF16>
__global__ __launch_bounds__(256)
void gemm_bt(const __hip_bfloat16* __restrict__ A, const __hip_bfloat16* __restrict__ BT,
             const float* __restrict__ biasA, const float* __restrict__ biasB, int bsplit,
             void* __restrict__ Cout, int M, int N, int K) {
  __shared__ __align__(16) __hip_bfloat16 As[128 * 32];
  __shared__ __align__(16) __hip_bfloat16 Bs[128 * 32];
  const int tid = threadIdx.x;
  const int lane = tid & 63;
  const int wid = tid >> 6;
  const int wr = wid >> 1, wc = wid & 1;
  const int fr = lane & 15, fq = lane >> 4;
  const int m0 = blockIdx.y * 128;
  const int n0 = blockIdx.x * 128;

  const __hip_bfloat16* Ag = A + (size_t)(m0 + (tid >> 2)) * K + (tid & 3) * 8;
  const __hip_bfloat16* Ag2 = Ag + (size_t)64 * K;
  const __hip_bfloat16* Bg = BT + (size_t)(n0 + (tid >> 2)) * K + (tid & 3) * 8;
  const __hip_bfloat16* Bg2 = Bg + (size_t)64 * K;
  char* AsB = (char*)&As[0] + wid * 1024;
  char* BsB = (char*)&Bs[0] + wid * 1024;

  f32x4 acc[4][4] = {};

  const int ksteps = K >> 5;
  for (int ks = 0; ks < ksteps; ++ks) {
    __syncthreads();
    gload16(Ag, AsB);
    gload16(Ag2, AsB + 4096);
    gload16(Bg, BsB);
    gload16(Bg2, BsB + 4096);
    Ag += 32; Ag2 += 32; Bg += 32; Bg2 += 32;
    __syncthreads();

    bf16x8 af[4], bfr[4];
#pragma unroll
    for (int i = 0; i < 4; ++i)
      af[i] = *(const bf16x8*)&As[(wr * 64 + i * 16 + fr) * 32 + fq * 8];
#pragma unroll
    for (int j = 0; j < 4; ++j)
      bfr[j] = *(const bf16x8*)&Bs[(wc * 64 + j * 16 + fr) * 32 + fq * 8];
#pragma unroll
    for (int i = 0; i < 4; ++i)
#pragma unroll
      for (int j = 0; j < 4; ++j)
        acc[i][j] = __builtin_amdgcn_mfma_f32_16x16x32_bf16(af[i], bfr[j], acc[i][j], 0, 0, 0);
  }

#pragma unroll
  for (int j = 0; j < 4; ++j) {
    int col = n0 + wc * 64 + j * 16 + fr;
    float bv = (col < bsplit) ? biasA[col] : biasB[col - bsplit];
#pragma unroll
    for (int i = 0; i < 4; ++i) {
#pragma unroll
      for (int r = 0; r < 4; ++r) {
        int row = m0 + wr * 64 + i * 16 + fq * 4 + r;
        float v = fmaxf(acc[i][j][r] + bv, 0.f);
        if (OUT_BF16)
          ((__hip_bfloat16*)Cout)[(size_t)row * N + col] = __float2bfloat16(v);
        else
          ((float*)Cout)[(size_t)row * N + col] = v;
      }
    }
  }
}

// ---------------- 256^2 stream-K GEMM (T2+T3+T4+T5 inner loop, verbatim) ----------
// Total K-iterations = 12800 for both GEMMs; grid = 256 blocks x 50 iters exactly.
// A tile (KT iters, KT<=32<50) spans at most 2 blocks. Later block = producer:
// stores bf16 partial + agent-scope release flag; earlier block = owner: acquire,
// add, write. All 256 blocks co-resident (128KiB LDS => 1 block/CU) => no deadlock.

#define LOAD_A(a, cb) do { _Pragma("unroll") for (int i = 0; i < 4; ++i) { \
  af[i][0] = *(const bf16x8*)((cb) + aoff0 + ((a)*4+i)*2048); \
  af[i][1] = *(const bf16x8*)((cb) + aoff1 + ((a)*4+i)*2048); } } while(0)

#define LOAD_B(b, BF, cb) do { _Pragma("unroll") for (int j = 0; j < 2; ++j) { \
  BF[j][0] = *(const bf16x8*)((cb) + boff0 + ((b)*2+j)*2048); \
  BF[j][1] = *(const bf16x8*)((cb) + boff1 + ((b)*2+j)*2048); } } while(0)

#define MFMA_Q(a, b, BF) do { _Pragma("unroll") for (int i = 0; i < 4; ++i) \
  _Pragma("unroll") for (int j = 0; j < 2; ++j) { \
    acc[(a)*4+i][(b)*2+j] = __builtin_amdgcn_mfma_f32_16x16x32_bf16(af[i][0], BF[j][0], acc[(a)*4+i][(b)*2+j], 0, 0, 0); \
    acc[(a)*4+i][(b)*2+j] = __builtin_amdgcn_mfma_f32_16x16x32_bf16(af[i][1], BF[j][1], acc[(a)*4+i][(b)*2+j], 0, 0, 0); } } while(0)

template <int KT_L2, int NTN_L2>
__global__ __launch_bounds__(512, 2)
void gemm256_sk(const __hip_bfloat16* __restrict__ A, const __hip_bfloat16* __restrict__ BT,
                const float* __restrict__ biasA, const float* __restrict__ biasB, int bsplit,
                __hip_bfloat16* __restrict__ Cout,
                __hip_bfloat16* __restrict__ pbuf, int* __restrict__ flags) {
  constexpr int KT = 1 << KT_L2;       // K-tiles per output tile
  constexpr int K = KT << 6;           // BK=64
  constexpr int NTN = 1 << NTN_L2;     // n-tiles per row of tiles
  constexpr int N = NTN << 8;
  constexpr int TOTAL = 12800;
  extern __shared__ char lds[];        // 131072 bytes

  const int tid = threadIdx.x;
  const int lane = tid & 63;
  const int wid = tid >> 6;
  const int wr = wid >> 2, wc = wid & 3;
  const int fr = lane & 15, fq = lane >> 4;
  const int b = blockIdx.x;
  const int iBeg = b * 50, iEnd = iBeg + 50;

  // staging source (pre-swizzled chunk), same as round 4
  const int rowA = tid >> 3;                 // 0..63
  const int c8v = (tid & 7) ^ (rowA & 7);
  const int kcol = c8v * 8;

  // swizzled LDS read offsets (byte), same as round 4
  const int x0 = fq ^ (fr & 7);
  const int aoff0 = wr * 16384 + fr * 128 + x0 * 16;
  const int aoff1 = wr * 16384 + fr * 128 + (x0 ^ 4) * 16;
  const int boff0 = 32768 + (wc >> 1) * 16384 + ((wc & 1) * 64 + fr) * 128 + x0 * 16;
  const int boff1 = 32768 + (wc >> 1) * 16384 + ((wc & 1) * 64 + fr) * 128 + (x0 ^ 4) * 16;

  auto stage2 = [&](const __hip_bfloat16* base, char* dst) {
    gload16(base, dst + wid * 1024);
    gload16(base + (size_t)64 * K, dst + 8192 + wid * 1024);
  };
  auto srcA = [&](int i, int h) {
    int t = i >> KT_L2, kt = i & (KT - 1);
    int m0 = (t >> NTN_L2) << 8;
    return A + (size_t)(m0 + h * 128 + rowA) * K + (kt << 6) + kcol;
  };
  auto srcB = [&](int i, int h) {
    int t = i >> KT_L2, kt = i & (KT - 1);
    int n0 = (t & (NTN - 1)) << 8;
    return BT + (size_t)(n0 + h * 128 + rowA) * K + (kt << 6) + kcol;
  };

  f32x4 acc[8][4] = {};
  bf16x8 af[4][2], bfA[2][2], bfB[2][2];

  auto writeC = [&](int t) {
    const int m0 = (t >> NTN_L2) << 8;
    const int n0 = (t & (NTN - 1)) << 8;
#pragma unroll
    for (int nj = 0; nj < 4; ++nj) {
      const int col = n0 + wc * 64 + nj * 16 + fr;
      const float bv = (col < bsplit) ? biasA[col] : biasB[col - bsplit];
#pragma unroll
      for (int mi = 0; mi < 8; ++mi) {
#pragma unroll
        for (int r = 0; r < 4; ++r) {
          const int row = m0 + wr * 128 + mi * 16 + fq * 4 + r;
          Cout[(size_t)row * N + col] = __float2bfloat16(fmaxf(acc[mi][nj][r] + bv, 0.f));
        }
      }
    }
  };

  // prologue: stage iter iBeg into buf parity (iBeg&1); 8 loads in flight
  {
    char* nb = lds + (iBeg & 1) * 65536;
    stage2(srcA(iBeg, 0), nb);
    stage2(srcA(iBeg, 1), nb + 16384);
    stage2(srcB(iBeg, 0), nb + 32768);
    stage2(srcB(iBeg, 1), nb + 49152);
  }

  for (int i = iBeg; i < iEnd; ++i) {
    char* cb = lds + (i & 1) * 65536;
    char* nb = lds + ((i & 1) ^ 1) * 65536;
    const int in = (i + 1 < TOTAL) ? i + 1 : TOTAL - 1;  // clamp (block 255 last iter)
    // -------- phase 0: stage A-half0(next); wait cur landed; compute Q(0,0)
    __builtin_amdgcn_s_barrier();            // all waves done reading buffer 'nb'
    __builtin_amdgcn_sched_barrier(0);
    stage2(srcA(in, 0), nb);
    __builtin_amdgcn_sched_barrier(0);
    asm volatile("s_waitcnt vmcnt(2)" ::: "memory");  // cur's 8 loads landed; 2 new in flight
    __builtin_amdgcn_s_barrier();            // cur visible to all waves
    __builtin_amdgcn_sched_barrier(0);
    LOAD_A(0, cb);
    LOAD_B(0, bfA, cb);
    __builtin_amdgcn_s_setprio(1); MFMA_Q(0, 0, bfA); __builtin_amdgcn_s_setprio(0);
    // -------- phase 1: stage A-half1; compute Q(0,1)
    __builtin_amdgcn_s_barrier();
    __builtin_amdgcn_sched_barrier(0);
    stage2(srcA(in, 1), nb + 16384);
    LOAD_B(1, bfB, cb);
    __builtin_amdgcn_s_setprio(1); MFMA_Q(0, 1, bfB); __builtin_amdgcn_s_setprio(0);
    // -------- phase 2: stage B-half0; compute Q(1,1)
    __builtin_amdgcn_s_barrier();
    __builtin_amdgcn_sched_barrier(0);
    stage2(srcB(in, 0), nb + 32768);
    LOAD_A(1, cb);
    __builtin_amdgcn_s_setprio(1); MFMA_Q(1, 1, bfB); __builtin_amdgcn_s_setprio(0);
    // -------- phase 3: stage B-half1; compute Q(1,0)
    __builtin_amdgcn_s_barrier();
    __builtin_amdgcn_sched_barrier(0);
    stage2(srcB(in, 1), nb + 49152);
    __builtin_amdgcn_s_setprio(1); MFMA_Q(1, 0, bfA); __builtin_amdgcn_s_setprio(0);

    // -------- tile boundary handling
    const int kt = i & (KT - 1);
    if (kt == KT - 1 || i == iEnd - 1) {
      const int t = i >> KT_L2;
      const bool ownStart = ((t << KT_L2) >= iBeg);
      const bool complete = (kt == KT - 1);
      if (ownStart && complete) {
        writeC(t);
      } else if (!ownStart) {
        // producer: store bf16 partial of tile tail, release flag
        __hip_bfloat16* slot = pbuf + (size_t)b * 65536 + tid * 128;
#pragma unroll
        for (int mi = 0; mi < 8; ++mi) {
#pragma unroll
          for (int nh = 0; nh < 2; ++nh) {
            bf16x8 v;
#pragma unroll
            for (int e = 0; e < 8; ++e)
              v[e] = (short)f2bu(acc[mi][nh * 2 + (e >> 2)][e & 3]);
            *reinterpret_cast<bf16x8*>(slot + mi * 16 + nh * 8) = v;
          }
        }
        __syncthreads();  // drains each wave's stores (vmcnt 0) before release
        if (tid == 0)
          __hip_atomic_store(&flags[b], 1, __ATOMIC_RELEASE, __HIP_MEMORY_SCOPE_AGENT);
      } else {
        // owner of incomplete tile: acquire producer (b+1) partial, add, write
        if (tid == 0) {
          while (__hip_atomic_load(&flags[b + 1], __ATOMIC_ACQUIRE,
                                   __HIP_MEMORY_SCOPE_AGENT) == 0)
            __builtin_amdgcn_s_sleep(2);
        }
        __syncthreads();
        __threadfence();  // invalidate caches on every wave before cross-XCD reads
        const __hip_bfloat16* slot = pbuf + (size_t)(b + 1) * 65536 + tid * 128;
#pragma unroll
        for (int mi = 0; mi < 8; ++mi) {
#pragma unroll
          for (int nh = 0; nh < 2; ++nh) {
            bf16x8 v = *reinterpret_cast<const bf16x8*>(slot + mi * 16 + nh * 8);
#pragma unroll
            for (int e = 0; e < 8; ++e)
              acc[mi][nh * 2 + (e >> 2)][e & 3] += bu2f((unsigned short)v[e]);
          }
        }
        writeC(t);
      }
      // reset accumulator for next tile
#pragma unroll
      for (int mi = 0; mi < 8; ++mi)
#pragma unroll
        for (int nj = 0; nj < 4; ++nj)
          acc[mi][nj] = f32x4{0.f, 0.f, 0.f, 0.f};
    }
  }
  // drain stray prefetch loads before workgroup retire (LDS writes in flight)
  asm volatile("s_waitcnt vmcnt(0)" ::: "memory");
}

// ---------------- launch ----------------

extern "C" void kernel_launch(void* const* d_in, const int* in_sizes, int n_in,
                              void* d_out, int out_size, void* d_ws, size_t ws_size,
                              hipStream_t stream) {
  const float* motion = (const float*)d_in[0];
  const float* robot  = (const float*)d_in[1];
  const float* z      = (const float*)d_in[2];
  const float* W_ms   = (const float*)d_in[3];
  const float* b_ms   = (const float*)d_in[4];
  const float* W_rs   = (const float*)d_in[5];
  const float* b_rs   = (const float*)d_in[6];
  const float* W_cmb  = (const float*)d_in[7];
  const float* b_cmb  = (const float*)d_in[8];
  const float* W_om   = (const float*)d_in[9];
  const float* b_om   = (const float*)d_in[10];
  const float* W_mu   = (const float*)d_in[11];
  const float* b_mu   = (const float*)d_in[12];
  const float* W_b    = (const float*)d_in[13];
  const float* b_b    = (const float*)d_in[14];
  const float* Wr0    = (const float*)d_in[15];
  const float* Wi0    = (const float*)d_in[16];
  const float* br0    = (const float*)d_in[17];
  const float* bi0    = (const float*)d_in[18];
  const float* Wr1    = (const float*)d_in[19];
  const float* Wi1    = (const float*)d_in[20];
  const float* br1    = (const float*)d_in[21];
  const float* bi1    = (const float*)d_in[22];
  const float* Wr2    = (const float*)d_in[23];
  const float* Wi2    = (const float*)d_in[24];
  const float* br2    = (const float*)d_in[25];
  // bi2 (d_in[26]) unused: yi of last layer is sliced away by [:, :, :256]

  float* out  = (float*)d_out;            // [25600,256], m = b*100+t
  float* zout = out + (size_t)6553600;    // [256,1024]
  float* omg  = zout + 262144;            // [256]
  float* muo  = omg + 256;                // [256,512]
  float* bbo  = muo + 131072;             // [256,512]

  char* ws = (char*)d_ws;
  __hip_bfloat16* BT0 = (__hip_bfloat16*)ws;               // [2048,1024]
  __hip_bfloat16* BT1 = BT0 + (size_t)2048 * 1024;         // [1024,2048]
  __hip_bfloat16* BT2 = BT1 + (size_t)1024 * 2048;         // [256,1024]
  __hip_bfloat16* A0  = BT2 + (size_t)256 * 1024;          // [25600,1024]
  __hip_bfloat16* C1  = A0 + (size_t)25600 * 1024;         // [25600,2048]
  __hip_bfloat16* C2  = C1 + (size_t)25600 * 2048;         // [25600,1024]
  int* flags = (int*)(C2 + (size_t)25600 * 1024);          // 512 ints
  // stream-K partial buffers live in regions dead at their time of use:
  __hip_bfloat16* pbuf1 = C2;   // during GEMM1 (C2 written later by GEMM2)
  __hip_bfloat16* pbuf2 = A0;   // during GEMM2 (A0 dead after GEMM1)

  front<<<256, 512, 0, stream>>>(motion, robot, z, W_ms, b_ms, W_rs, b_rs,
                                 W_cmb, b_cmb, W_mu, b_mu, W_b, b_b, W_om, b_om,
                                 A0, zout, omg, muo, bbo, flags);

  tpack_all<<<4352, dim3(32, 8), 0, stream>>>(Wr0, Wi0, Wr1, Wi1, Wr2, Wi2,
                                              BT0, BT1, BT2);

  // GEMM1: [25600,1024] x [2048,1024]^T -> C1 bf16.  800 tiles x 16 = 12800 iters
  gemm256_sk<4, 3><<<256, 512, 131072, stream>>>(A0, BT0, br0, bi0, 1024, C1,
                                                 pbuf1, flags);
  // GEMM2: [25600,2048] x [1024,2048]^T -> C2 bf16.  400 tiles x 32 = 12800 iters
  gemm256_sk<5, 2><<<256, 512, 131072, stream>>>(C1, BT1, br1, bi1, 512, C2,
                                                 pbuf2, flags + 256);
  // GEMM3: [25600,1024] x [256,1024]^T -> out f32 (small; proven 128^2 kernel)
  gemm_bt<0><<<dim3(2, 200), 256, 0, stream>>>(C2, BT2, br2, br2, 256, out,
                                               25600, 256, 1024);
}

// Round 6
// 447.303 us; speedup vs baseline: 1.2929x; 1.2929x over previous
//
#include <hip/hip_runtime.h>
#include <hip/hip_bf16.h>

#define STEPS 100
#define DTC 0.001f

typedef __attribute__((ext_vector_type(8))) short bf16x8;
typedef __attribute__((ext_vector_type(4))) float f32x4;

__device__ __forceinline__ void gload16(const void* g, void* l) {
  __builtin_amdgcn_global_load_lds(
      (const __attribute__((address_space(1))) void*)g,
      (__attribute__((address_space(3))) void*)l,
      16, 0, 0);
}

// ---------------- fused front: enc1+enc2+enc3+hopf (all row-b-local, fp32) ----------

__global__ __launch_bounds__(512)
void front(const float* __restrict__ ms_in, const float* __restrict__ rs_in,
           const float* __restrict__ z,
           const float* __restrict__ Wms, const float* __restrict__ bms,
           const float* __restrict__ Wrs, const float* __restrict__ brs,
           const float* __restrict__ Wc, const float* __restrict__ bc,
           const float* __restrict__ Wmu, const float* __restrict__ bmu,
           const float* __restrict__ Wb, const float* __restrict__ bbias,
           const float* __restrict__ Wom, const float* __restrict__ bom,
           __hip_bfloat16* __restrict__ A0, float* __restrict__ z_out,
           float* __restrict__ om_out, float* __restrict__ mu_out,
           float* __restrict__ bb_out, int* __restrict__ flags) {
  const int b = blockIdx.x;
  const int n = threadIdx.x;  // 512
  if (b == 0) flags[n] = 0;   // zero panel_done flags (512 ints) before fused GEMM
  __shared__ float sIn[192];
  __shared__ float stA[512];
  __shared__ float stB[512];
  if (n < 64) sIn[n] = ms_in[b * 64 + n];
  else if (n < 192) sIn[n] = rs_in[b * 128 + (n - 64)];
  __syncthreads();
  // enc1
  float a1;
  if (n < 256) {
    a1 = bms[n];
    for (int k = 0; k < 64; ++k) a1 += sIn[k] * Wms[k * 256 + n];
  } else {
    int nn = n - 256;
    a1 = brs[nn];
    for (int k = 0; k < 128; ++k) a1 += sIn[64 + k] * Wrs[k * 256 + nn];
  }
  stA[n] = fmaxf(a1, 0.f);
  __syncthreads();
  // enc2
  float a2 = bc[n];
  for (int k = 0; k < 512; ++k) a2 += stA[k] * Wc[k * 512 + n];
  stB[n] = fmaxf(a2, 0.f);
  __syncthreads();
  // enc3: mu, b, omega
  float am = bmu[n], ab = bbias[n];
  for (int k = 0; k < 512; ++k) {
    float sv = stB[k];
    am += sv * Wmu[k * 512 + n];
    ab += sv * Wb[k * 512 + n];
  }
  const float muv = fabsf(fmaxf(am, 0.f));
  const float bbv = fabsf(fmaxf(ab, 0.f));
  mu_out[b * 512 + n] = muv;
  bb_out[b * 512 + n] = bbv;
  stA[n] = stB[n] * Wom[n];  // W_om is [512,1]; reuse stA as reduction buffer
  __syncthreads();
  for (int off = 256; off > 0; off >>= 1) {
    if (n < off) stA[n] += stA[n + off];
    __syncthreads();
  }
  const float om = fabsf(fmaxf(stA[0] + bom[0], 0.f));
  if (n == 0) om_out[b] = om;
  // hopf trajectory (fp32 state; bf16 GEMM input, M-order m = b*100 + t)
  float x = z[b * 1024 + n];
  float y = z[b * 1024 + 512 + n];
  const float w = om * (float)(n + 1);
  for (int t = 0; t < STEPS; ++t) {
    float r2 = x * x + y * y;
    float g = muv - r2;
    float nx = x + DTC * (g * x - w * y + bbv);
    float ny = y + DTC * (g * y + w * x);
    x = nx; y = ny;
    if (t == 0) {
      z_out[b * 1024 + n] = x;
      z_out[b * 1024 + 512 + n] = y;
    }
    size_t row = (size_t)b * STEPS + t;
    A0[row * 1024 + n] = __float2bfloat16(x);
    A0[row * 1024 + 512 + n] = __float2bfloat16(y);
  }
}

// ---------------- all 10 weight transposes in one kernel ----------------

__constant__ int    jSrcC[10] = {0, 1, 1, 0, 2, 3, 3, 2, 4, 5};
__constant__ float  jSgnC[10] = {1.f, 1.f, -1.f, 1.f, 1.f, 1.f, -1.f, 1.f, 1.f, -1.f};
__constant__ int    jCC[10]   = {1024, 1024, 1024, 1024, 512, 512, 512, 512, 256, 256};
__constant__ int    jDstC[10] = {0, 0, 0, 0, 1, 1, 1, 1, 2, 2};
__constant__ int    jDsC[10]  = {1024, 1024, 1024, 1024, 2048, 2048, 2048, 2048, 1024, 1024};
__constant__ long   jOffC[10] = {0, 1048576, 512, 1049088, 0, 1048576, 1024, 1049600, 0, 512};

__global__ void tpack_all(const float* __restrict__ Wr0, const float* __restrict__ Wi0,
                          const float* __restrict__ Wr1, const float* __restrict__ Wi1,
                          const float* __restrict__ Wr2, const float* __restrict__ Wi2,
                          __hip_bfloat16* __restrict__ BT0, __hip_bfloat16* __restrict__ BT1,
                          __hip_bfloat16* __restrict__ BT2) {
  __shared__ float tile[32][33];
  const int bid = blockIdx.x;
  int j, w;
  if (bid < 4096) { j = bid >> 9; w = bid & 511; }
  else            { j = 8 + ((bid - 4096) >> 7); w = (bid - 4096) & 127; }
  const float* srcs[6] = {Wr0, Wi0, Wr1, Wi1, Wr2, Wi2};
  __hip_bfloat16* dsts[3] = {BT0, BT1, BT2};
  const float* src = srcs[jSrcC[j]];
  __hip_bfloat16* dst = dsts[jDstC[j]] + jOffC[j];
  const int C = jCC[j], ds = jDsC[j];
  const float sign = jSgnC[j];
  const int ncb = C >> 5;
  const int cb = (w % ncb) * 32, rb = (w / ncb) * 32;
  const int tx = threadIdx.x, ty = threadIdx.y;  // (32,8)
#pragma unroll
  for (int i = 0; i < 32; i += 8)
    tile[ty + i][tx] = src[(size_t)(rb + ty + i) * C + (cb + tx)];
  __syncthreads();
#pragma unroll
  for (int i = 0; i < 32; i += 8)
    dst[(size_t)(cb + ty + i) * ds + (rb + tx)] = __float2bfloat16(sign * tile[tx][ty + i]);
}

// ---------------- 128^2 bf16 MFMA GEMM (kept for GEMM3) ----------------

template <int OUT_BF16>
__global__ __launch_bounds__(256)
void gemm_bt(const __hip_bfloat16* __restrict__ A, const __hip_bfloat16* __restrict__ BT,
             const float* __restrict__ biasA, const float* __restrict__ biasB, int bsplit,
             void* __restrict__ Cout, int M, int N, int K) {
  __shared__ __align__(16) __hip_bfloat16 As[128 * 32];
  __shared__ __align__(16) __hip_bfloat16 Bs[128 * 32];
  const int tid = threadIdx.x;
  const int lane = tid & 63;
  const int wid = tid >> 6;
  const int wr = wid >> 1, wc = wid & 1;
  const int fr = lane & 15, fq = lane >> 4;
  const int m0 = blockIdx.y * 128;
  const int n0 = blockIdx.x * 128;

  const __hip_bfloat16* Ag = A + (size_t)(m0 + (tid >> 2)) * K + (tid & 3) * 8;
  const __hip_bfloat16* Ag2 = Ag + (size_t)64 * K;
  const __hip_bfloat16* Bg = BT + (size_t)(n0 + (tid >> 2)) * K + (tid & 3) * 8;
  const __hip_bfloat16* Bg2 = Bg + (size_t)64 * K;
  char* AsB = (char*)&As[0] + wid * 1024;
  char* BsB = (char*)&Bs[0] + wid * 1024;

  f32x4 acc[4][4] = {};

  const int ksteps = K >> 5;
  for (int ks = 0; ks < ksteps; ++ks) {
    __syncthreads();
    gload16(Ag, AsB);
    gload16(Ag2, AsB + 4096);
    gload16(Bg, BsB);
    gload16(Bg2, BsB + 4096);
    Ag += 32; Ag2 += 32; Bg += 32; Bg2 += 32;
    __syncthreads();

    bf16x8 af[4], bfr[4];
#pragma unroll
    for (int i = 0; i < 4; ++i)
      af[i] = *(const bf16x8*)&As[(wr * 64 + i * 16 + fr) * 32 + fq * 8];
#pragma unroll
    for (int j = 0; j < 4; ++j)
      bfr[j] = *(const bf16x8*)&Bs[(wc * 64 + j * 16 + fr) * 32 + fq * 8];
#pragma unroll
    for (int i = 0; i < 4; ++i)
#pragma unroll
      for (int j = 0; j < 4; ++j)
        acc[i][j] = __builtin_amdgcn_mfma_f32_16x16x32_bf16(af[i], bfr[j], acc[i][j], 0, 0, 0);
  }

#pragma unroll
  for (int j = 0; j < 4; ++j) {
    int col = n0 + wc * 64 + j * 16 + fr;
    float bv = (col < bsplit) ? biasA[col] : biasB[col - bsplit];
#pragma unroll
    for (int i = 0; i < 4; ++i) {
#pragma unroll
      for (int r = 0; r < 4; ++r) {
        int row = m0 + wr * 64 + i * 16 + fq * 4 + r;
        float v = fmaxf(acc[i][j][r] + bv, 0.f);
        if (OUT_BF16)
          ((__hip_bfloat16*)Cout)[(size_t)row * N + col] = __float2bfloat16(v);
        else
          ((float*)Cout)[(size_t)row * N + col] = v;
      }
    }
  }
}

// ---------------- fused persistent GEMM1+GEMM2 ----------------
// Round-4's proven 4-phase 256^2 tile loop as a device function; persistent
// 256-block grid walks a static XCD-swizzled work list (3-4 G1 tiles, then
// 0-2 G2 tiles). G2 tile (mt,nt) needs C1 panel mt = 8 G1 tiles; panel_done
// counters (release/acquire, agent scope — pattern HW-validated in round 5)
// gate it. Assignment is timed so deps are ready on arrival (no steady spin).

#define LOAD_A(a, cb) do { _Pragma("unroll") for (int i = 0; i < 4; ++i) { \
  af[i][0] = *(const bf16x8*)((cb) + aoff0 + ((a)*4+i)*2048); \
  af[i][1] = *(const bf16x8*)((cb) + aoff1 + ((a)*4+i)*2048); } } while(0)

#define LOAD_B(b, BF, cb) do { _Pragma("unroll") for (int j = 0; j < 2; ++j) { \
  BF[j][0] = *(const bf16x8*)((cb) + boff0 + ((b)*2+j)*2048); \
  BF[j][1] = *(const bf16x8*)((cb) + boff1 + ((b)*2+j)*2048); } } while(0)

#define MFMA_Q(a, b, BF) do { _Pragma("unroll") for (int i = 0; i < 4; ++i) \
  _Pragma("unroll") for (int j = 0; j < 2; ++j) { \
    acc[(a)*4+i][(b)*2+j] = __builtin_amdgcn_mfma_f32_16x16x32_bf16(af[i][0], BF[j][0], acc[(a)*4+i][(b)*2+j], 0, 0, 0); \
    acc[(a)*4+i][(b)*2+j] = __builtin_amdgcn_mfma_f32_16x16x32_bf16(af[i][1], BF[j][1], acc[(a)*4+i][(b)*2+j], 0, 0, 0); } } while(0)

template <int KT_L2, int NTN_L2>
__device__ void tile_gemm(const __hip_bfloat16* __restrict__ A,
                          const __hip_bfloat16* __restrict__ BT,
                          const float* __restrict__ biasA, const float* __restrict__ biasB,
                          int bsplit, __hip_bfloat16* __restrict__ Cout,
                          int mt, int nt, char* lds) {
  constexpr int KT = 1 << KT_L2;
  constexpr int K = KT << 6;
  constexpr int N = 256 << NTN_L2;
  const int tid = threadIdx.x;
  const int lane = tid & 63;
  const int wid = tid >> 6;
  const int wr = wid >> 2, wc = wid & 3;
  const int fr = lane & 15, fq = lane >> 4;
  const int m0 = mt << 8, n0 = nt << 8;

  // staging source (pre-swizzled chunk to match swizzled LDS reads — rule #21)
  const int rowA = tid >> 3;                 // 0..63
  const int c8v = (tid & 7) ^ (rowA & 7);
  const __hip_bfloat16* Abase = A + (size_t)(m0 + rowA) * K + c8v * 8;
  const __hip_bfloat16* Bbase = BT + (size_t)(n0 + rowA) * K + c8v * 8;

  // swizzled LDS read offsets (byte)
  const int x0 = fq ^ (fr & 7);
  const int aoff0 = wr * 16384 + fr * 128 + x0 * 16;
  const int aoff1 = wr * 16384 + fr * 128 + (x0 ^ 4) * 16;
  const int boff0 = 32768 + (wc >> 1) * 16384 + ((wc & 1) * 64 + fr) * 128 + x0 * 16;
  const int boff1 = 32768 + (wc >> 1) * 16384 + ((wc & 1) * 64 + fr) * 128 + (x0 ^ 4) * 16;

  auto stage2 = [&](const __hip_bfloat16* base, char* dst) {
    gload16(base, dst + wid * 1024);
    gload16(base + (size_t)64 * K, dst + 8192 + wid * 1024);
  };

  // all waves must be done with previous tile's LDS before we restage
  __builtin_amdgcn_s_barrier();

  // prologue: K-tile 0 -> buf 0 (8 loads in flight)
  stage2(Abase, lds);
  stage2(Abase + (size_t)128 * K, lds + 16384);
  stage2(Bbase, lds + 32768);
  stage2(Bbase + (size_t)128 * K, lds + 49152);

  f32x4 acc[8][4] = {};
  bf16x8 af[4][2], bfA[2][2], bfB[2][2];

  for (int kt = 0; kt < KT - 1; ++kt) {
    char* cb = lds + (kt & 1) * 65536;
    char* nb = lds + ((kt & 1) ^ 1) * 65536;
    const int ko = (kt + 1) << 6;
    // phase 0: stage A-half0(next); wait cur landed; compute Q(0,0)
    __builtin_amdgcn_s_barrier();
    __builtin_amdgcn_sched_barrier(0);
    stage2(Abase + ko, nb);
    __builtin_amdgcn_sched_barrier(0);
    asm volatile("s_waitcnt vmcnt(2)" ::: "memory");
    __builtin_amdgcn_s_barrier();
    __builtin_amdgcn_sched_barrier(0);
    LOAD_A(0, cb);
    LOAD_B(0, bfA, cb);
    __builtin_amdgcn_s_setprio(1); MFMA_Q(0, 0, bfA); __builtin_amdgcn_s_setprio(0);
    // phase 1: stage A-half1; compute Q(0,1)
    __builtin_amdgcn_s_barrier();
    __builtin_amdgcn_sched_barrier(0);
    stage2(Abase + (size_t)128 * K + ko, nb + 16384);
    LOAD_B(1, bfB, cb);
    __builtin_amdgcn_s_setprio(1); MFMA_Q(0, 1, bfB); __builtin_amdgcn_s_setprio(0);
    // phase 2: stage B-half0; compute Q(1,1)
    __builtin_amdgcn_s_barrier();
    __builtin_amdgcn_sched_barrier(0);
    stage2(Bbase + ko, nb + 32768);
    LOAD_A(1, cb);
    __builtin_amdgcn_s_setprio(1); MFMA_Q(1, 1, bfB); __builtin_amdgcn_s_setprio(0);
    // phase 3: stage B-half1; compute Q(1,0)
    __builtin_amdgcn_s_barrier();
    __builtin_amdgcn_sched_barrier(0);
    stage2(Bbase + (size_t)128 * K + ko, nb + 49152);
    __builtin_amdgcn_s_setprio(1); MFMA_Q(1, 0, bfA); __builtin_amdgcn_s_setprio(0);
  }
  // final K-tile: compute-only (no stage -> no cross-tile strays)
  {
    char* cb = lds + ((KT - 1) & 1) * 65536;
    __builtin_amdgcn_s_barrier();
    asm volatile("s_waitcnt vmcnt(0)" ::: "memory");
    __builtin_amdgcn_s_barrier();
    __builtin_amdgcn_sched_barrier(0);
    LOAD_A(0, cb);
    LOAD_B(0, bfA, cb);
    __builtin_amdgcn_s_setprio(1); MFMA_Q(0, 0, bfA); __builtin_amdgcn_s_setprio(0);
    LOAD_B(1, bfB, cb);
    __builtin_amdgcn_s_setprio(1); MFMA_Q(0, 1, bfB); __builtin_amdgcn_s_setprio(0);
    LOAD_A(1, cb);
    __builtin_amdgcn_s_setprio(1); MFMA_Q(1, 1, bfB); MFMA_Q(1, 0, bfA); __builtin_amdgcn_s_setprio(0);
  }

  // epilogue: bias + relu, bf16 store. C/D layout: col=lane&15, row=(lane>>4)*4+reg
#pragma unroll
  for (int nj = 0; nj < 4; ++nj) {
    const int col = n0 + wc * 64 + nj * 16 + fr;
    const float bv = (col < bsplit) ? biasA[col] : biasB[col - bsplit];
#pragma unroll
    for (int mi = 0; mi < 8; ++mi) {
#pragma unroll
      for (int r = 0; r < 4; ++r) {
        const int row = m0 + wr * 128 + mi * 16 + fq * 4 + r;
        Cout[(size_t)row * N + col] = __float2bfloat16(fmaxf(acc[mi][nj][r] + bv, 0.f));
      }
    }
  }
}

__global__ __launch_bounds__(512, 2)
void gemm_fused(const __hip_bfloat16* __restrict__ A0, const __hip_bfloat16* __restrict__ BT0,
                const float* __restrict__ br0, const float* __restrict__ bi0,
                __hip_bfloat16* __restrict__ C1, const __hip_bfloat16* __restrict__ BT1,
                const float* __restrict__ br1, const float* __restrict__ bi1,
                __hip_bfloat16* __restrict__ C2, int* __restrict__ panel_done) {
  extern __shared__ char lds[];  // 131072 B
  const int b = blockIdx.x;      // grid = 256, 1 block/CU (128KiB LDS), all co-resident
  const int tid = threadIdx.x;

  // ---- GEMM1: 800 tiles (mt 0..99, nt 0..7), 16 iters each.
  // Static XCD-swizzled slots: same-XCD blocks (b = x mod 8) take consecutive
  // tiles -> round-4 L2 locality. Slots 0..2 cover g<768; blocks 0..31 take slot 3.
  const int swzb = (b & 7) * 32 + (b >> 3);           // bijective [0,256)
  const int n1 = (b < 32) ? 4 : 3;
  for (int s = 0; s < n1; ++s) {
    const int g = (s < 3) ? (s << 8) + swzb
                          : 768 + ((b & 7) << 2) + (b >> 3);  // bijective [768,800)
    const int mt = g >> 3, nt = g & 7;
    tile_gemm<4, 3>(A0, BT0, br0, bi0, 1024, C1, mt, nt, lds);
    __syncthreads();  // drains all waves' C1 stores (vmcnt 0) before release
    if (tid == 0)
      __hip_atomic_fetch_add(&panel_done[mt], 1, __ATOMIC_RELEASE,
                             __HIP_MEMORY_SCOPE_AGENT);
  }

  // ---- GEMM2: 400 tiles (mt 0..99, nt 0..3), 32 iters each.
  // First wave: blocks 32..255 get h in [0,224) (mt<56; panels done by slot 1).
  // Second wave: blocks 32..175 get h in [224,368) (mt<92; done by slot 2).
  // Blocks 0..31 get h in [368,400) (mt 92..99; ready as they arrive at t=64u).
  int hv0 = -1, hv1 = -1;
  if (b >= 32) {
    const int v = b - 32;                 // [0,224)
    hv0 = (v & 7) * 28 + (v >> 3);        // bijective [0,224)
    if (v < 144) hv1 = 224 + (v & 7) * 18 + (v >> 3);  // bijective [224,368)
  } else {
    hv0 = 368 + ((b & 7) << 2) + (b >> 3);             // bijective [368,400)
  }
#pragma unroll
  for (int q = 0; q < 2; ++q) {
    const int h = (q == 0) ? hv0 : hv1;
    if (h < 0) continue;
    const int mt = h >> 2, nt = h & 3;
    if (tid == 0) {
      while (__hip_atomic_load(&panel_done[mt], __ATOMIC_ACQUIRE,
                               __HIP_MEMORY_SCOPE_AGENT) < 8)
        __builtin_amdgcn_s_sleep(2);
    }
    __syncthreads();
    __threadfence();  // invalidate caches on every wave before cross-XCD reads
    tile_gemm<5, 2>(C1, BT1, br1, bi1, 512, C2, mt, nt, lds);
  }
}

// ---------------- launch ----------------

extern "C" void kernel_launch(void* const* d_in, const int* in_sizes, int n_in,
                              void* d_out, int out_size, void* d_ws, size_t ws_size,
                              hipStream_t stream) {
  const float* motion = (const float*)d_in[0];
  const float* robot  = (const float*)d_in[1];
  const float* z      = (const float*)d_in[2];
  const float* W_ms   = (const float*)d_in[3];
  const float* b_ms   = (const float*)d_in[4];
  const float* W_rs   = (const float*)d_in[5];
  const float* b_rs   = (const float*)d_in[6];
  const float* W_cmb  = (const float*)d_in[7];
  const float* b_cmb  = (const float*)d_in[8];
  const float* W_om   = (const float*)d_in[9];
  const float* b_om   = (const float*)d_in[10];
  const float* W_mu   = (const float*)d_in[11];
  const float* b_mu   = (const float*)d_in[12];
  const float* W_b    = (const float*)d_in[13];
  const float* b_b    = (const float*)d_in[14];
  const float* Wr0    = (const float*)d_in[15];
  const float* Wi0    = (const float*)d_in[16];
  const float* br0    = (const float*)d_in[17];
  const float* bi0    = (const float*)d_in[18];
  const float* Wr1    = (const float*)d_in[19];
  const float* Wi1    = (const float*)d_in[20];
  const float* br1    = (const float*)d_in[21];
  const float* bi1    = (const float*)d_in[22];
  const float* Wr2    = (const float*)d_in[23];
  const float* Wi2    = (const float*)d_in[24];
  const float* br2    = (const float*)d_in[25];
  // bi2 (d_in[26]) unused: yi of last layer is sliced away by [:, :, :256]

  float* out  = (float*)d_out;            // [25600,256], m = b*100+t
  float* zout = out + (size_t)6553600;    // [256,1024]
  float* omg  = zout + 262144;            // [256]
  float* muo  = omg + 256;                // [256,512]
  float* bbo  = muo + 131072;             // [256,512]

  char* ws = (char*)d_ws;
  __hip_bfloat16* BT0 = (__hip_bfloat16*)ws;               // [2048,1024]
  __hip_bfloat16* BT1 = BT0 + (size_t)2048 * 1024;         // [1024,2048]
  __hip_bfloat16* BT2 = BT1 + (size_t)1024 * 2048;         // [256,1024]
  __hip_bfloat16* A0  = BT2 + (size_t)256 * 1024;          // [25600,1024]
  __hip_bfloat16* C1  = A0 + (size_t)25600 * 1024;         // [25600,2048]
  __hip_bfloat16* C2  = C1 + (size_t)25600 * 2048;         // [25600,1024]
  int* flags = (int*)(C2 + (size_t)25600 * 1024);          // 512 ints (panel_done)

  front<<<256, 512, 0, stream>>>(motion, robot, z, W_ms, b_ms, W_rs, b_rs,
                                 W_cmb, b_cmb, W_mu, b_mu, W_b, b_b, W_om, b_om,
                                 A0, zout, omg, muo, bbo, flags);

  tpack_all<<<4352, dim3(32, 8), 0, stream>>>(Wr0, Wi0, Wr1, Wi1, Wr2, Wi2,
                                              BT0, BT1, BT2);

  // fused GEMM1 ([25600,1024]x[2048,1024]^T->C1) + GEMM2 ([25600,2048]x[1024,2048]^T->C2)
  gemm_fused<<<256, 512, 131072, stream>>>(A0, BT0, br0, bi0, C1, BT1, br1, bi1,
                                           C2, flags);

  // GEMM3: [25600,1024] x [256,1024]^T -> out f32 (small; proven 128^2 kernel)
  gemm_bt<0><<<dim3(2, 200), 256, 0, stream>>>(C2, BT2, br2, br2, 256, out,
                                               25600, 256, 1024);
}

// Round 7
// 322.615 us; speedup vs baseline: 1.7926x; 1.3865x over previous
//
#include <hip/hip_runtime.h>
#include <hip/hip_bf16.h>

#define STEPS 100
#define DTC 0.001f

typedef __attribute__((ext_vector_type(8))) short bf16x8;
typedef __attribute__((ext_vector_type(4))) float f32x4;

__device__ __forceinline__ void gload16(const void* g, void* l) {
  __builtin_amdgcn_global_load_lds(
      (const __attribute__((address_space(1))) void*)g,
      (__attribute__((address_space(3))) void*)l,
      16, 0, 0);
}

// ---------------- fused front: enc1+enc2+enc3+hopf (all row-b-local, fp32) ----------

__global__ __launch_bounds__(512)
void front(const float* __restrict__ ms_in, const float* __restrict__ rs_in,
           const float* __restrict__ z,
           const float* __restrict__ Wms, const float* __restrict__ bms,
           const float* __restrict__ Wrs, const float* __restrict__ brs,
           const float* __restrict__ Wc, const float* __restrict__ bc,
           const float* __restrict__ Wmu, const float* __restrict__ bmu,
           const float* __restrict__ Wb, const float* __restrict__ bbias,
           const float* __restrict__ Wom, const float* __restrict__ bom,
           __hip_bfloat16* __restrict__ A0, float* __restrict__ z_out,
           float* __restrict__ om_out, float* __restrict__ mu_out,
           float* __restrict__ bb_out) {
  const int b = blockIdx.x;
  const int n = threadIdx.x;  // 512
  __shared__ float sIn[192];
  __shared__ float stA[512];
  __shared__ float stB[512];
  if (n < 64) sIn[n] = ms_in[b * 64 + n];
  else if (n < 192) sIn[n] = rs_in[b * 128 + (n - 64)];
  __syncthreads();
  // enc1
  float a1;
  if (n < 256) {
    a1 = bms[n];
    for (int k = 0; k < 64; ++k) a1 += sIn[k] * Wms[k * 256 + n];
  } else {
    int nn = n - 256;
    a1 = brs[nn];
    for (int k = 0; k < 128; ++k) a1 += sIn[64 + k] * Wrs[k * 256 + nn];
  }
  stA[n] = fmaxf(a1, 0.f);
  __syncthreads();
  // enc2
  float a2 = bc[n];
  for (int k = 0; k < 512; ++k) a2 += stA[k] * Wc[k * 512 + n];
  stB[n] = fmaxf(a2, 0.f);
  __syncthreads();
  // enc3: mu, b, omega
  float am = bmu[n], ab = bbias[n];
  for (int k = 0; k < 512; ++k) {
    float sv = stB[k];
    am += sv * Wmu[k * 512 + n];
    ab += sv * Wb[k * 512 + n];
  }
  const float muv = fabsf(fmaxf(am, 0.f));
  const float bbv = fabsf(fmaxf(ab, 0.f));
  mu_out[b * 512 + n] = muv;
  bb_out[b * 512 + n] = bbv;
  stA[n] = stB[n] * Wom[n];  // W_om is [512,1]; reuse stA as reduction buffer
  __syncthreads();
  for (int off = 256; off > 0; off >>= 1) {
    if (n < off) stA[n] += stA[n + off];
    __syncthreads();
  }
  const float om = fabsf(fmaxf(stA[0] + bom[0], 0.f));
  if (n == 0) om_out[b] = om;
  // hopf trajectory (fp32 state; bf16 GEMM input, M-order m = b*100 + t)
  float x = z[b * 1024 + n];
  float y = z[b * 1024 + 512 + n];
  const float w = om * (float)(n + 1);
  for (int t = 0; t < STEPS; ++t) {
    float r2 = x * x + y * y;
    float g = muv - r2;
    float nx = x + DTC * (g * x - w * y + bbv);
    float ny = y + DTC * (g * y + w * x);
    x = nx; y = ny;
    if (t == 0) {
      z_out[b * 1024 + n] = x;
      z_out[b * 1024 + 512 + n] = y;
    }
    size_t row = (size_t)b * STEPS + t;
    A0[row * 1024 + n] = __float2bfloat16(x);
    A0[row * 1024 + 512 + n] = __float2bfloat16(y);
  }
}

// ---------------- all 10 weight transposes in one kernel ----------------

__constant__ int    jSrcC[10] = {0, 1, 1, 0, 2, 3, 3, 2, 4, 5};
__constant__ float  jSgnC[10] = {1.f, 1.f, -1.f, 1.f, 1.f, 1.f, -1.f, 1.f, 1.f, -1.f};
__constant__ int    jCC[10]   = {1024, 1024, 1024, 1024, 512, 512, 512, 512, 256, 256};
__constant__ int    jDstC[10] = {0, 0, 0, 0, 1, 1, 1, 1, 2, 2};
__constant__ int    jDsC[10]  = {1024, 1024, 1024, 1024, 2048, 2048, 2048, 2048, 1024, 1024};
__constant__ long   jOffC[10] = {0, 1048576, 512, 1049088, 0, 1048576, 1024, 1049600, 0, 512};

__global__ void tpack_all(const float* __restrict__ Wr0, const float* __restrict__ Wi0,
                          const float* __restrict__ Wr1, const float* __restrict__ Wi1,
                          const float* __restrict__ Wr2, const float* __restrict__ Wi2,
                          __hip_bfloat16* __restrict__ BT0, __hip_bfloat16* __restrict__ BT1,
                          __hip_bfloat16* __restrict__ BT2) {
  __shared__ float tile[32][33];
  const int bid = blockIdx.x;
  int j, w;
  if (bid < 4096) { j = bid >> 9; w = bid & 511; }
  else            { j = 8 + ((bid - 4096) >> 7); w = (bid - 4096) & 127; }
  const float* srcs[6] = {Wr0, Wi0, Wr1, Wi1, Wr2, Wi2};
  __hip_bfloat16* dsts[3] = {BT0, BT1, BT2};
  const float* src = srcs[jSrcC[j]];
  __hip_bfloat16* dst = dsts[jDstC[j]] + jOffC[j];
  const int C = jCC[j], ds = jDsC[j];
  const float sign = jSgnC[j];
  const int ncb = C >> 5;
  const int cb = (w % ncb) * 32, rb = (w / ncb) * 32;
  const int tx = threadIdx.x, ty = threadIdx.y;  // (32,8)
#pragma unroll
  for (int i = 0; i < 32; i += 8)
    tile[ty + i][tx] = src[(size_t)(rb + ty + i) * C + (cb + tx)];
  __syncthreads();
#pragma unroll
  for (int i = 0; i < 32; i += 8)
    dst[(size_t)(cb + ty + i) * ds + (rb + tx)] = __float2bfloat16(sign * tile[tx][ty + i]);
}

// ---------------- 128^2 bf16 MFMA GEMM (kept for GEMM3) ----------------

template <int OUT_BF16>
__global__ __launch_bounds__(256)
void gemm_bt(const __hip_bfloat16* __restrict__ A, const __hip_bfloat16* __restrict__ BT,
             const float* __restrict__ biasA, const float* __restrict__ biasB, int bsplit,
             void* __restrict__ Cout, int M, int N, int K) {
  __shared__ __align__(16) __hip_bfloat16 As[128 * 32];
  __shared__ __align__(16) __hip_bfloat16 Bs[128 * 32];
  const int tid = threadIdx.x;
  const int lane = tid & 63;
  const int wid = tid >> 6;
  const int wr = wid >> 1, wc = wid & 1;
  const int fr = lane & 15, fq = lane >> 4;
  const int m0 = blockIdx.y * 128;
  const int n0 = blockIdx.x * 128;

  const __hip_bfloat16* Ag = A + (size_t)(m0 + (tid >> 2)) * K + (tid & 3) * 8;
  const __hip_bfloat16* Ag2 = Ag + (size_t)64 * K;
  const __hip_bfloat16* Bg = BT + (size_t)(n0 + (tid >> 2)) * K + (tid & 3) * 8;
  const __hip_bfloat16* Bg2 = Bg + (size_t)64 * K;
  char* AsB = (char*)&As[0] + wid * 1024;
  char* BsB = (char*)&Bs[0] + wid * 1024;

  f32x4 acc[4][4] = {};

  const int ksteps = K >> 5;
  for (int ks = 0; ks < ksteps; ++ks) {
    __syncthreads();
    gload16(Ag, AsB);
    gload16(Ag2, AsB + 4096);
    gload16(Bg, BsB);
    gload16(Bg2, BsB + 4096);
    Ag += 32; Ag2 += 32; Bg += 32; Bg2 += 32;
    __syncthreads();

    bf16x8 af[4], bfr[4];
#pragma unroll
    for (int i = 0; i < 4; ++i)
      af[i] = *(const bf16x8*)&As[(wr * 64 + i * 16 + fr) * 32 + fq * 8];
#pragma unroll
    for (int j = 0; j < 4; ++j)
      bfr[j] = *(const bf16x8*)&Bs[(wc * 64 + j * 16 + fr) * 32 + fq * 8];
#pragma unroll
    for (int i = 0; i < 4; ++i)
#pragma unroll
      for (int j = 0; j < 4; ++j)
        acc[i][j] = __builtin_amdgcn_mfma_f32_16x16x32_bf16(af[i], bfr[j], acc[i][j], 0, 0, 0);
  }

#pragma unroll
  for (int j = 0; j < 4; ++j) {
    int col = n0 + wc * 64 + j * 16 + fr;
    float bv = (col < bsplit) ? biasA[col] : biasB[col - bsplit];
#pragma unroll
    for (int i = 0; i < 4; ++i) {
#pragma unroll
      for (int r = 0; r < 4; ++r) {
        int row = m0 + wr * 64 + i * 16 + fq * 4 + r;
        float v = fmaxf(acc[i][j][r] + bv, 0.f);
        if (OUT_BF16)
          ((__hip_bfloat16*)Cout)[(size_t)row * N + col] = __float2bfloat16(v);
        else
          ((float*)Cout)[(size_t)row * N + col] = v;
      }
    }
  }
}

// ---------------- 256^2 8-wave bf16 MFMA GEMM, software-pipelined ds_reads ------
// Round-4 launch/grid/vmcnt schedule (proven) + hoisted operand loads:
// each phase's ds_reads are issued one phase early; MFMA waits use COUNTED
// lgkmcnt (never 0 mid-tile). sched_barrier(0) pins issue order (rule #18).

#define LOAD_A(DST, a, cb) do { _Pragma("unroll") for (int i = 0; i < 4; ++i) { \
  DST[i][0] = *(const bf16x8*)((cb) + aoff0 + ((a)*4+i)*2048); \
  DST[i][1] = *(const bf16x8*)((cb) + aoff1 + ((a)*4+i)*2048); } } while(0)

#define LOAD_B(b, BF, cb) do { _Pragma("unroll") for (int j = 0; j < 2; ++j) { \
  BF[j][0] = *(const bf16x8*)((cb) + boff0 + ((b)*2+j)*2048); \
  BF[j][1] = *(const bf16x8*)((cb) + boff1 + ((b)*2+j)*2048); } } while(0)

#define MFMA_Q(ASET, a, b, BF) do { _Pragma("unroll") for (int i = 0; i < 4; ++i) \
  _Pragma("unroll") for (int j = 0; j < 2; ++j) { \
    acc[(a)*4+i][(b)*2+j] = __builtin_amdgcn_mfma_f32_16x16x32_bf16(ASET[i][0], BF[j][0], acc[(a)*4+i][(b)*2+j], 0, 0, 0); \
    acc[(a)*4+i][(b)*2+j] = __builtin_amdgcn_mfma_f32_16x16x32_bf16(ASET[i][1], BF[j][1], acc[(a)*4+i][(b)*2+j], 0, 0, 0); } } while(0)

#define SBAR __builtin_amdgcn_sched_barrier(0)

__global__ __launch_bounds__(512, 2)
void gemm256(const __hip_bfloat16* __restrict__ A, const __hip_bfloat16* __restrict__ BT,
             const float* __restrict__ biasA, const float* __restrict__ biasB, int bsplit,
             __hip_bfloat16* __restrict__ Cout, int N, int K, int ntn) {
  extern __shared__ char lds[];  // 131072 bytes

  const int tid = threadIdx.x;
  const int lane = tid & 63;
  const int wid = tid >> 6;       // 0..7
  const int wr = wid >> 2;        // 0..1  (M half)
  const int wc = wid & 3;         // 0..3  (N quarter)
  const int fr = lane & 15, fq = lane >> 4;

  // XCD-aware bijective swizzle (grid % 8 == 0 guaranteed by launch)
  const int nwg = gridDim.x;
  int f = blockIdx.x;
  f = (f & 7) * (nwg >> 3) + (f >> 3);
  const int m0 = (f / ntn) * 256;
  const int n0 = (f % ntn) * 256;

  // staging source (pre-swizzled chunk): thread t covers row (t>>3), chunk c8v
  const int c8v = (tid & 7) ^ ((tid >> 3) & 7);
  const __hip_bfloat16* Asrc0 = A + (size_t)(m0 + (tid >> 3)) * K + c8v * 8;
  const __hip_bfloat16* Asrc1 = Asrc0 + (size_t)128 * K;
  const __hip_bfloat16* Bsrc0 = BT + (size_t)(n0 + (tid >> 3)) * K + c8v * 8;
  const __hip_bfloat16* Bsrc1 = Bsrc0 + (size_t)128 * K;

  // swizzled LDS read offsets (byte): slot = rowInHalf*8 + ((ks*4+fq) ^ (fr&7))
  const int x0 = fq ^ (fr & 7);
  const int aoff0 = wr * 16384 + fr * 128 + x0 * 16;
  const int aoff1 = wr * 16384 + fr * 128 + (x0 ^ 4) * 16;
  const int boff0 = 32768 + (wc >> 1) * 16384 + ((wc & 1) * 64 + fr) * 128 + x0 * 16;
  const int boff1 = 32768 + (wc >> 1) * 16384 + ((wc & 1) * 64 + fr) * 128 + (x0 ^ 4) * 16;

  auto stage2 = [&](const __hip_bfloat16* base, char* dst) {
    gload16(base, dst + wid * 1024);
    gload16(base + (size_t)64 * K, dst + 8192 + wid * 1024);
  };

  // prologue: tile 0 -> buf 0 (8 loads in flight)
  stage2(Asrc0, 0 + lds);
  stage2(Asrc1, lds + 16384);
  stage2(Bsrc0, lds + 32768);
  stage2(Bsrc1, lds + 49152);

  f32x4 acc[8][4] = {};
  bf16x8 af[4][2], ag[4][2], bfA[2][2], bfB[2][2];

  const int nk = K >> 6;
  for (int kt = 0; kt < nk - 1; ++kt) {
    const int cur = kt & 1;
    char* cb = lds + cur * 65536;
    char* nb = lds + (cur ^ 1) * 65536;
    const int ko = (kt + 1) << 6;
    // ---- phase 0: stage A-h0(next); vmcnt(2) -> cur tile landed; issue Q00+Q01 reads
    __builtin_amdgcn_s_barrier();            // all waves done reading buffer 'nb'
    SBAR;
    stage2(Asrc0 + ko, nb);
    SBAR;
    asm volatile("s_waitcnt vmcnt(2)" ::: "memory");  // cur's 8 loads landed; 2 new in flight
    __builtin_amdgcn_s_barrier();            // cur visible to all waves
    SBAR;
    LOAD_A(af, 0, cb);      // 8 ds_read_b128
    LOAD_B(0, bfA, cb);     // 4
    SBAR;                   // pin group order before bfB
    LOAD_B(1, bfB, cb);     // 4 (for Q01, next phase)
    asm volatile("s_waitcnt lgkmcnt(4)" ::: "memory");  // af+bfA done; bfB in flight
    SBAR;
    __builtin_amdgcn_s_setprio(1); MFMA_Q(af, 0, 0, bfA); __builtin_amdgcn_s_setprio(0);
    // ---- phase 1: stage A-h1; issue Q1x A-reads (ag); compute Q01
    __builtin_amdgcn_s_barrier();
    SBAR;
    stage2(Asrc1 + ko, nb + 16384);
    LOAD_A(ag, 1, cb);      // 8 (for Q11/Q10, later phases)
    asm volatile("s_waitcnt lgkmcnt(8)" ::: "memory");  // bfB done; ag in flight
    SBAR;
    __builtin_amdgcn_s_setprio(1); MFMA_Q(af, 0, 1, bfB); __builtin_amdgcn_s_setprio(0);
    // ---- phase 2: stage B-h0; compute Q11
    __builtin_amdgcn_s_barrier();
    SBAR;
    stage2(Bsrc0 + ko, nb + 32768);
    asm volatile("s_waitcnt lgkmcnt(0)" ::: "memory");  // ag done
    SBAR;
    __builtin_amdgcn_s_setprio(1); MFMA_Q(ag, 1, 1, bfB); __builtin_amdgcn_s_setprio(0);
    // ---- phase 3: stage B-h1; compute Q10 (all operands a phase old)
    __builtin_amdgcn_s_barrier();
    SBAR;
    stage2(Bsrc1 + ko, nb + 49152);
    SBAR;
    __builtin_amdgcn_s_setprio(1); MFMA_Q(ag, 1, 0, bfA); __builtin_amdgcn_s_setprio(0);
  }
  // ---- final tile: compute-only
  {
    char* cb = lds + ((nk - 1) & 1) * 65536;
    __builtin_amdgcn_s_barrier();
    asm volatile("s_waitcnt vmcnt(0)" ::: "memory");
    __builtin_amdgcn_s_barrier();
    SBAR;
    LOAD_A(af, 0, cb);
    LOAD_B(0, bfA, cb);
    SBAR;
    LOAD_B(1, bfB, cb);
    asm volatile("s_waitcnt lgkmcnt(4)" ::: "memory");
    SBAR;
    __builtin_amdgcn_s_setprio(1); MFMA_Q(af, 0, 0, bfA); __builtin_amdgcn_s_setprio(0);
    LOAD_A(ag, 1, cb);
    asm volatile("s_waitcnt lgkmcnt(8)" ::: "memory");
    SBAR;
    __builtin_amdgcn_s_setprio(1); MFMA_Q(af, 0, 1, bfB); __builtin_amdgcn_s_setprio(0);
    asm volatile("s_waitcnt lgkmcnt(0)" ::: "memory");
    SBAR;
    __builtin_amdgcn_s_setprio(1); MFMA_Q(ag, 1, 1, bfB); MFMA_Q(ag, 1, 0, bfA);
    __builtin_amdgcn_s_setprio(0);
  }

  // epilogue: bias + relu, bf16 store. C/D layout: col=lane&15, row=(lane>>4)*4+reg
#pragma unroll
  for (int nj = 0; nj < 4; ++nj) {
    const int col = n0 + wc * 64 + nj * 16 + fr;
    const float bv = (col < bsplit) ? biasA[col] : biasB[col - bsplit];
#pragma unroll
    for (int mi = 0; mi < 8; ++mi) {
#pragma unroll
      for (int r = 0; r < 4; ++r) {
        const int row = m0 + wr * 128 + mi * 16 + fq * 4 + r;
        float v = fmaxf(acc[mi][nj][r] + bv, 0.f);
        Cout[(size_t)row * N + col] = __float2bfloat16(v);
      }
    }
  }
}

// ---------------- launch ----------------

extern "C" void kernel_launch(void* const* d_in, const int* in_sizes, int n_in,
                              void* d_out, int out_size, void* d_ws, size_t ws_size,
                              hipStream_t stream) {
  const float* motion = (const float*)d_in[0];
  const float* robot  = (const float*)d_in[1];
  const float* z      = (const float*)d_in[2];
  const float* W_ms   = (const float*)d_in[3];
  const float* b_ms   = (const float*)d_in[4];
  const float* W_rs   = (const float*)d_in[5];
  const float* b_rs   = (const float*)d_in[6];
  const float* W_cmb  = (const float*)d_in[7];
  const float* b_cmb  = (const float*)d_in[8];
  const float* W_om   = (const float*)d_in[9];
  const float* b_om   = (const float*)d_in[10];
  const float* W_mu   = (const float*)d_in[11];
  const float* b_mu   = (const float*)d_in[12];
  const float* W_b    = (const float*)d_in[13];
  const float* b_b    = (const float*)d_in[14];
  const float* Wr0    = (const float*)d_in[15];
  const float* Wi0    = (const float*)d_in[16];
  const float* br0    = (const float*)d_in[17];
  const float* bi0    = (const float*)d_in[18];
  const float* Wr1    = (const float*)d_in[19];
  const float* Wi1    = (const float*)d_in[20];
  const float* br1    = (const float*)d_in[21];
  const float* bi1    = (const float*)d_in[22];
  const float* Wr2    = (const float*)d_in[23];
  const float* Wi2    = (const float*)d_in[24];
  const float* br2    = (const float*)d_in[25];
  // bi2 (d_in[26]) unused: yi of last layer is sliced away by [:, :, :256]

  float* out  = (float*)d_out;            // [25600,256], m = b*100+t
  float* zout = out + (size_t)6553600;    // [256,1024]
  float* omg  = zout + 262144;            // [256]
  float* muo  = omg + 256;                // [256,512]
  float* bbo  = muo + 131072;             // [256,512]

  char* ws = (char*)d_ws;
  __hip_bfloat16* BT0 = (__hip_bfloat16*)ws;               // [2048,1024]
  __hip_bfloat16* BT1 = BT0 + (size_t)2048 * 1024;         // [1024,2048]
  __hip_bfloat16* BT2 = BT1 + (size_t)1024 * 2048;         // [256,1024]
  __hip_bfloat16* A0  = BT2 + (size_t)256 * 1024;          // [25600,1024]
  __hip_bfloat16* C1  = A0 + (size_t)25600 * 1024;         // [25600,2048]
  __hip_bfloat16* C2  = C1 + (size_t)25600 * 2048;         // [25600,1024]

  front<<<256, 512, 0, stream>>>(motion, robot, z, W_ms, b_ms, W_rs, b_rs,
                                 W_cmb, b_cmb, W_mu, b_mu, W_b, b_b, W_om, b_om,
                                 A0, zout, omg, muo, bbo);

  tpack_all<<<4352, dim3(32, 8), 0, stream>>>(Wr0, Wi0, Wr1, Wi1, Wr2, Wi2,
                                              BT0, BT1, BT2);

  // GEMM1: [25600,1024] x [2048,1024]^T -> C1 bf16   (100x8 = 800 blocks, %8==0)
  gemm256<<<800, 512, 131072, stream>>>(A0, BT0, br0, bi0, 1024, C1, 2048, 1024, 8);
  // GEMM2: [25600,2048] x [1024,2048]^T -> C2 bf16   (100x4 = 400 blocks, %8==0)
  gemm256<<<400, 512, 131072, stream>>>(C1, BT1, br1, bi1, 512, C2, 1024, 2048, 4);
  // GEMM3: [25600,1024] x [256,1024]^T -> out f32 (small; proven 128^2 kernel)
  gemm_bt<0><<<dim3(2, 200), 256, 0, stream>>>(C2, BT2, br2, br2, 256, out,
                                               25600, 256, 1024);
}

// Round 8
// 298.525 us; speedup vs baseline: 1.9373x; 1.0807x over previous
//
#include <hip/hip_runtime.h>
#include <hip/hip_bf16.h>

#define STEPS 100
#define DTC 0.001f

typedef __attribute__((ext_vector_type(8))) short bf16x8;
typedef __attribute__((ext_vector_type(4))) float f32x4;

__device__ __forceinline__ void gload16(const void* g, void* l) {
  __builtin_amdgcn_global_load_lds(
      (const __attribute__((address_space(1))) void*)g,
      (__attribute__((address_space(3))) void*)l,
      16, 0, 0);
}

// ---------------- fused front: enc1+enc2+enc3+hopf (all row-b-local, fp32) ----------

__global__ __launch_bounds__(512)
void front(const float* __restrict__ ms_in, const float* __restrict__ rs_in,
           const float* __restrict__ z,
           const float* __restrict__ Wms, const float* __restrict__ bms,
           const float* __restrict__ Wrs, const float* __restrict__ brs,
           const float* __restrict__ Wc, const float* __restrict__ bc,
           const float* __restrict__ Wmu, const float* __restrict__ bmu,
           const float* __restrict__ Wb, const float* __restrict__ bbias,
           const float* __restrict__ Wom, const float* __restrict__ bom,
           __hip_bfloat16* __restrict__ A0, float* __restrict__ z_out,
           float* __restrict__ om_out, float* __restrict__ mu_out,
           float* __restrict__ bb_out) {
  const int b = blockIdx.x;
  const int n = threadIdx.x;  // 512
  __shared__ float sIn[192];
  __shared__ float stA[512];
  __shared__ float stB[512];
  if (n < 64) sIn[n] = ms_in[b * 64 + n];
  else if (n < 192) sIn[n] = rs_in[b * 128 + (n - 64)];
  __syncthreads();
  // enc1
  float a1;
  if (n < 256) {
    a1 = bms[n];
    for (int k = 0; k < 64; ++k) a1 += sIn[k] * Wms[k * 256 + n];
  } else {
    int nn = n - 256;
    a1 = brs[nn];
    for (int k = 0; k < 128; ++k) a1 += sIn[64 + k] * Wrs[k * 256 + nn];
  }
  stA[n] = fmaxf(a1, 0.f);
  __syncthreads();
  // enc2
  float a2 = bc[n];
  for (int k = 0; k < 512; ++k) a2 += stA[k] * Wc[k * 512 + n];
  stB[n] = fmaxf(a2, 0.f);
  __syncthreads();
  // enc3: mu, b, omega
  float am = bmu[n], ab = bbias[n];
  for (int k = 0; k < 512; ++k) {
    float sv = stB[k];
    am += sv * Wmu[k * 512 + n];
    ab += sv * Wb[k * 512 + n];
  }
  const float muv = fabsf(fmaxf(am, 0.f));
  const float bbv = fabsf(fmaxf(ab, 0.f));
  mu_out[b * 512 + n] = muv;
  bb_out[b * 512 + n] = bbv;
  stA[n] = stB[n] * Wom[n];  // W_om is [512,1]; reuse stA as reduction buffer
  __syncthreads();
  for (int off = 256; off > 0; off >>= 1) {
    if (n < off) stA[n] += stA[n + off];
    __syncthreads();
  }
  const float om = fabsf(fmaxf(stA[0] + bom[0], 0.f));
  if (n == 0) om_out[b] = om;
  // hopf trajectory (fp32 state; bf16 GEMM input, M-order m = b*100 + t)
  float x = z[b * 1024 + n];
  float y = z[b * 1024 + 512 + n];
  const float w = om * (float)(n + 1);
  for (int t = 0; t < STEPS; ++t) {
    float r2 = x * x + y * y;
    float g = muv - r2;
    float nx = x + DTC * (g * x - w * y + bbv);
    float ny = y + DTC * (g * y + w * x);
    x = nx; y = ny;
    if (t == 0) {
      z_out[b * 1024 + n] = x;
      z_out[b * 1024 + 512 + n] = y;
    }
    size_t row = (size_t)b * STEPS + t;
    A0[row * 1024 + n] = __float2bfloat16(x);
    A0[row * 1024 + 512 + n] = __float2bfloat16(y);
  }
}

// ---------------- all 10 weight transposes in one kernel ----------------

__constant__ int    jSrcC[10] = {0, 1, 1, 0, 2, 3, 3, 2, 4, 5};
__constant__ float  jSgnC[10] = {1.f, 1.f, -1.f, 1.f, 1.f, 1.f, -1.f, 1.f, 1.f, -1.f};
__constant__ int    jCC[10]   = {1024, 1024, 1024, 1024, 512, 512, 512, 512, 256, 256};
__constant__ int    jDstC[10] = {0, 0, 0, 0, 1, 1, 1, 1, 2, 2};
__constant__ int    jDsC[10]  = {1024, 1024, 1024, 1024, 2048, 2048, 2048, 2048, 1024, 1024};
__constant__ long   jOffC[10] = {0, 1048576, 512, 1049088, 0, 1048576, 1024, 1049600, 0, 512};

__global__ void tpack_all(const float* __restrict__ Wr0, const float* __restrict__ Wi0,
                          const float* __restrict__ Wr1, const float* __restrict__ Wi1,
                          const float* __restrict__ Wr2, const float* __restrict__ Wi2,
                          __hip_bfloat16* __restrict__ BT0, __hip_bfloat16* __restrict__ BT1,
                          __hip_bfloat16* __restrict__ BT2) {
  __shared__ float tile[32][33];
  const int bid = blockIdx.x;
  int j, w;
  if (bid < 4096) { j = bid >> 9; w = bid & 511; }
  else            { j = 8 + ((bid - 4096) >> 7); w = (bid - 4096) & 127; }
  const float* srcs[6] = {Wr0, Wi0, Wr1, Wi1, Wr2, Wi2};
  __hip_bfloat16* dsts[3] = {BT0, BT1, BT2};
  const float* src = srcs[jSrcC[j]];
  __hip_bfloat16* dst = dsts[jDstC[j]] + jOffC[j];
  const int C = jCC[j], ds = jDsC[j];
  const float sign = jSgnC[j];
  const int ncb = C >> 5;
  const int cb = (w % ncb) * 32, rb = (w / ncb) * 32;
  const int tx = threadIdx.x, ty = threadIdx.y;  // (32,8)
#pragma unroll
  for (int i = 0; i < 32; i += 8)
    tile[ty + i][tx] = src[(size_t)(rb + ty + i) * C + (cb + tx)];
  __syncthreads();
#pragma unroll
  for (int i = 0; i < 32; i += 8)
    dst[(size_t)(cb + ty + i) * ds + (rb + tx)] = __float2bfloat16(sign * tile[tx][ty + i]);
}

// ---------------- 160x128 bf16 MFMA GEMM, exact-grid (zero tail) ----------------
// A [M,K] row-major bf16; BT [N,K] row-major bf16. C = relu(A@BT^T + bias).
// BM=160, BN=128, BK=64; 256 threads = 4 waves (2Mx2N), per-wave 80x64.
// M=25600 -> 160 m-tiles; tiles = 160*(N/128): G1 2560 = 10x256, G2 1280 = 5x256,
// G3 320 -- zero (or tiny) scheduling tail. LDS 72KiB -> 2 blocks/CU: independent
// blocks absorb each other's barrier/vmcnt stalls (m114 overlap).
// Same proven swizzle (pre-swizzled source, XOR read) and 4-phase vmcnt(2)/counted
// lgkmcnt schedule as rounds 4-7. Loads per K-tile = 9 (A:5, B:4).

#define SBAR __builtin_amdgcn_sched_barrier(0)

#define RD_A(DST, QX, cb) do { _Pragma("unroll") for (int mi = 0; mi < 5; ++mi) \
  DST[mi] = *(const bf16x8*)((cb) + (abase ^ ((QX) * 64)) + mi * 2048); } while (0)

#define RD_B(DST, h, QX, cb) do { _Pragma("unroll") for (int jj = 0; jj < 2; ++jj) \
  DST[jj] = *(const bf16x8*)((cb) + (bbase ^ ((QX) * 64)) + (2 * (h) + jj) * 2048); } while (0)

#define MF_PH(ASET, BSET, h) do { _Pragma("unroll") for (int mi = 0; mi < 5; ++mi) \
  _Pragma("unroll") for (int jj = 0; jj < 2; ++jj) \
    acc[mi][2 * (h) + jj] = __builtin_amdgcn_mfma_f32_16x16x32_bf16( \
        ASET[mi], BSET[jj], acc[mi][2 * (h) + jj], 0, 0, 0); } while (0)

template <int OUT_BF16>
__global__ __launch_bounds__(256, 2)
void gemm160(const __hip_bfloat16* __restrict__ A, const __hip_bfloat16* __restrict__ BT,
             const float* __restrict__ biasA, const float* __restrict__ biasB, int bsplit,
             void* __restrict__ Cout, int N, int K, int ntn_l2) {
  extern __shared__ char lds[];  // 73728 B: 2 buf x (A 20480 | B 16384)

  const int tid = threadIdx.x;
  const int lane = tid & 63;
  const int wid = tid >> 6;       // 0..3
  const int wr = wid >> 1;        // M half (80 rows)
  const int wc = wid & 1;         // N half (64 cols)
  const int fr = lane & 15, fq = lane >> 4;

  // XCD-aware bijective swizzle (all grids here are %8==0)
  const int nwg = gridDim.x;
  int f = blockIdx.x;
  f = (f & 7) * (nwg >> 3) + (f >> 3);
  const int m0 = (f >> ntn_l2) * 160;
  const int n0 = (f & ((1 << ntn_l2) - 1)) << 7;

  // staging source (pre-swizzled chunk): thread t covers rows rA+32j, chunk c8v
  const int rA = tid >> 3;                  // 0..31
  const int c8v = (tid & 7) ^ (rA & 7);
  const __hip_bfloat16* Asrc = A + (size_t)(m0 + rA) * K + c8v * 8;
  const __hip_bfloat16* Bsrc = BT + (size_t)(n0 + rA) * K + c8v * 8;

  // swizzled LDS read offsets (byte): slot = row*8 + ((fq+4q) ^ (row&7));
  // 80/64/16 are all %8==0 so row&7 == fr&7.
  const int x0 = fq ^ (fr & 7);
  const int abase = (wr * 80 + fr) * 128 + x0 * 16;           // + mi*2048; ^64 for q=1
  const int bbase = 20480 + (wc * 64 + fr) * 128 + x0 * 16;   // + nj*2048; ^64 for q=1

  auto stgA = [&](int j, int ko, char* buf) {
    gload16(Asrc + ko + (size_t)32 * j * K, buf + j * 4096 + wid * 1024);
  };
  auto stgB = [&](int j, int ko, char* buf) {
    gload16(Bsrc + ko + (size_t)32 * j * K, buf + 20480 + j * 4096 + wid * 1024);
  };

  // prologue: tile 0 -> buf 0 (9 loads in flight)
  stgA(0, 0, lds); stgA(1, 0, lds); stgA(2, 0, lds); stgA(3, 0, lds); stgA(4, 0, lds);
  stgB(0, 0, lds); stgB(1, 0, lds); stgB(2, 0, lds); stgB(3, 0, lds);

  f32x4 acc[5][4] = {};
  bf16x8 a0[5], a1[5], b00[2], b10[2], b01[2], b11[2];

  const int nk = K >> 6;
  for (int kt = 0; kt < nk - 1; ++kt) {
    char* cb = lds + (kt & 1) * 36864;
    char* nb = lds + ((kt & 1) ^ 1) * 36864;
    const int ko = (kt + 1) << 6;
    // ---- phase 0: stage A0,A1(next); vmcnt(2) -> cur tile landed; MFMA (h0,q0)
    __builtin_amdgcn_s_barrier();            // all waves done reading 'nb'
    SBAR;
    stgA(0, ko, nb); stgA(1, ko, nb);
    SBAR;
    asm volatile("s_waitcnt vmcnt(2)" ::: "memory");  // cur's 9 loads landed; 2 new in flight
    __builtin_amdgcn_s_barrier();            // cur visible to all waves
    SBAR;
    RD_A(a0, 0, cb);        // 5 ds_read_b128
    RD_B(b00, 0, 0, cb);    // 2
    SBAR;                   // pin order before b10
    RD_B(b10, 1, 0, cb);    // 2 (for phase 1)
    asm volatile("s_waitcnt lgkmcnt(2)" ::: "memory");  // a0+b00 done; b10 in flight
    SBAR;
    __builtin_amdgcn_s_setprio(1); MF_PH(a0, b00, 0); __builtin_amdgcn_s_setprio(0);
    // ---- phase 1: stage A2..A4; issue q1 A-reads + b01; MFMA (h1,q0)
    __builtin_amdgcn_s_barrier();
    SBAR;
    stgA(2, ko, nb); stgA(3, ko, nb); stgA(4, ko, nb);
    RD_A(a1, 1, cb);        // 5 (for phases 2-3)
    RD_B(b01, 0, 1, cb);    // 2 (for phase 2)
    asm volatile("s_waitcnt lgkmcnt(7)" ::: "memory");  // b10 done; a1+b01 in flight
    SBAR;
    __builtin_amdgcn_s_setprio(1); MF_PH(a0, b10, 1); __builtin_amdgcn_s_setprio(0);
    // ---- phase 2: stage B0,B1; issue b11; MFMA (h0,q1)
    __builtin_amdgcn_s_barrier();
    SBAR;
    stgB(0, ko, nb); stgB(1, ko, nb);
    RD_B(b11, 1, 1, cb);    // 2 (for phase 3)
    asm volatile("s_waitcnt lgkmcnt(2)" ::: "memory");  // a1+b01 done; b11 in flight
    SBAR;
    __builtin_amdgcn_s_setprio(1); MF_PH(a1, b01, 0); __builtin_amdgcn_s_setprio(0);
    // ---- phase 3: stage B2,B3; MFMA (h1,q1)
    __builtin_amdgcn_s_barrier();
    SBAR;
    stgB(2, ko, nb); stgB(3, ko, nb);
    asm volatile("s_waitcnt lgkmcnt(0)" ::: "memory");
    SBAR;
    __builtin_amdgcn_s_setprio(1); MF_PH(a1, b11, 1); __builtin_amdgcn_s_setprio(0);
  }
  // ---- final tile: compute-only (no staging -> no stray loads)
  {
    char* cb = lds + ((nk - 1) & 1) * 36864;
    __builtin_amdgcn_s_barrier();
    asm volatile("s_waitcnt vmcnt(0)" ::: "memory");
    __builtin_amdgcn_s_barrier();
    SBAR;
    RD_A(a0, 0, cb);
    RD_B(b00, 0, 0, cb);
    SBAR;
    RD_B(b10, 1, 0, cb);
    asm volatile("s_waitcnt lgkmcnt(2)" ::: "memory");
    SBAR;
    __builtin_amdgcn_s_setprio(1); MF_PH(a0, b00, 0); __builtin_amdgcn_s_setprio(0);
    RD_A(a1, 1, cb);
    RD_B(b01, 0, 1, cb);
    asm volatile("s_waitcnt lgkmcnt(7)" ::: "memory");
    SBAR;
    __builtin_amdgcn_s_setprio(1); MF_PH(a0, b10, 1); __builtin_amdgcn_s_setprio(0);
    RD_B(b11, 1, 1, cb);
    asm volatile("s_waitcnt lgkmcnt(2)" ::: "memory");
    SBAR;
    __builtin_amdgcn_s_setprio(1); MF_PH(a1, b01, 0); __builtin_amdgcn_s_setprio(0);
    asm volatile("s_waitcnt lgkmcnt(0)" ::: "memory");
    SBAR;
    __builtin_amdgcn_s_setprio(1); MF_PH(a1, b11, 1); __builtin_amdgcn_s_setprio(0);
  }

  // epilogue: bias + relu. C/D layout: col=lane&15, row=(lane>>4)*4+reg
#pragma unroll
  for (int nj = 0; nj < 4; ++nj) {
    const int col = n0 + wc * 64 + nj * 16 + fr;
    const float bv = (col < bsplit) ? biasA[col] : biasB[col - bsplit];
#pragma unroll
    for (int mi = 0; mi < 5; ++mi) {
#pragma unroll
      for (int r = 0; r < 4; ++r) {
        const int row = m0 + wr * 80 + mi * 16 + fq * 4 + r;
        float v = fmaxf(acc[mi][nj][r] + bv, 0.f);
        if (OUT_BF16)
          ((__hip_bfloat16*)Cout)[(size_t)row * N + col] = __float2bfloat16(v);
        else
          ((float*)Cout)[(size_t)row * N + col] = v;
      }
    }
  }
}

// ---------------- launch ----------------

extern "C" void kernel_launch(void* const* d_in, const int* in_sizes, int n_in,
                              void* d_out, int out_size, void* d_ws, size_t ws_size,
                              hipStream_t stream) {
  const float* motion = (const float*)d_in[0];
  const float* robot  = (const float*)d_in[1];
  const float* z      = (const float*)d_in[2];
  const float* W_ms   = (const float*)d_in[3];
  const float* b_ms   = (const float*)d_in[4];
  const float* W_rs   = (const float*)d_in[5];
  const float* b_rs   = (const float*)d_in[6];
  const float* W_cmb  = (const float*)d_in[7];
  const float* b_cmb  = (const float*)d_in[8];
  const float* W_om   = (const float*)d_in[9];
  const float* b_om   = (const float*)d_in[10];
  const float* W_mu   = (const float*)d_in[11];
  const float* b_mu   = (const float*)d_in[12];
  const float* W_b    = (const float*)d_in[13];
  const float* b_b    = (const float*)d_in[14];
  const float* Wr0    = (const float*)d_in[15];
  const float* Wi0    = (const float*)d_in[16];
  const float* br0    = (const float*)d_in[17];
  const float* bi0    = (const float*)d_in[18];
  const float* Wr1    = (const float*)d_in[19];
  const float* Wi1    = (const float*)d_in[20];
  const float* br1    = (const float*)d_in[21];
  const float* bi1    = (const float*)d_in[22];
  const float* Wr2    = (const float*)d_in[23];
  const float* Wi2    = (const float*)d_in[24];
  const float* br2    = (const float*)d_in[25];
  // bi2 (d_in[26]) unused: yi of last layer is sliced away by [:, :, :256]

  float* out  = (float*)d_out;            // [25600,256], m = b*100+t
  float* zout = out + (size_t)6553600;    // [256,1024]
  float* omg  = zout + 262144;            // [256]
  float* muo  = omg + 256;                // [256,512]
  float* bbo  = muo + 131072;             // [256,512]

  char* ws = (char*)d_ws;
  __hip_bfloat16* BT0 = (__hip_bfloat16*)ws;               // [2048,1024]
  __hip_bfloat16* BT1 = BT0 + (size_t)2048 * 1024;         // [1024,2048]
  __hip_bfloat16* BT2 = BT1 + (size_t)1024 * 2048;         // [256,1024]
  __hip_bfloat16* A0  = BT2 + (size_t)256 * 1024;          // [25600,1024]
  __hip_bfloat16* C1  = A0 + (size_t)25600 * 1024;         // [25600,2048]
  __hip_bfloat16* C2  = C1 + (size_t)25600 * 2048;         // [25600,1024]

  front<<<256, 512, 0, stream>>>(motion, robot, z, W_ms, b_ms, W_rs, b_rs,
                                 W_cmb, b_cmb, W_mu, b_mu, W_b, b_b, W_om, b_om,
                                 A0, zout, omg, muo, bbo);

  tpack_all<<<4352, dim3(32, 8), 0, stream>>>(Wr0, Wi0, Wr1, Wi1, Wr2, Wi2,
                                              BT0, BT1, BT2);

  // GEMM1: [25600,1024] x [2048,1024]^T -> C1 bf16   (160x16 = 2560 = 10x256 exact)
  gemm160<1><<<2560, 256, 73728, stream>>>(A0, BT0, br0, bi0, 1024, C1, 2048, 1024, 4);
  // GEMM2: [25600,2048] x [1024,2048]^T -> C2 bf16   (160x8 = 1280 = 5x256 exact)
  gemm160<1><<<1280, 256, 73728, stream>>>(C1, BT1, br1, bi1, 512, C2, 1024, 2048, 3);
  // GEMM3: [25600,1024] x [256,1024]^T -> out f32    (160x2 = 320 tiles)
  gemm160<0><<<320, 256, 73728, stream>>>(C2, BT2, br2, br2, 256, out, 256, 1024, 1);
}